// Round 6
// baseline (411.605 us; speedup 1.0000x reference)
//
#include <hip/hip_runtime.h>
#include <math.h>

#define BB 4096
#define TT 200
#define NT (BB*TT)

// ---- prep: WE = Wa + Wc ----
__global__ __launch_bounds__(256) void k_prep_we(const float* __restrict__ auW1,
                                                 float* __restrict__ WE) {
  int i = blockIdx.x * 256 + threadIdx.x;
  if (i < 64 * 36) WE[i] = auW1[i] + auW1[128 * 36 + i];
}

// ---- prep: TBuf[b][36] = ie_b @ (Wb - Wc) + au_b1 ----
__global__ __launch_bounds__(64) void k_prep_tb(const int* __restrict__ item,
                                                const float* __restrict__ Itab,
                                                const float* __restrict__ auW1,
                                                const float* __restrict__ auB1,
                                                float* __restrict__ TBuf) {
  int b = blockIdx.x, tid = threadIdx.x;
  __shared__ float sIe[64];
  sIe[tid] = Itab[(size_t)item[b] * 64 + tid];
  __syncthreads();
  if (tid < 36) {
    float a = auB1[tid];
    for (int k = 0; k < 64; ++k)
      a += sIe[k] * (auW1[(64 + k) * 36 + tid] - auW1[(128 + k) * 36 + tid]);
    TBuf[b * 36 + tid] = a;
  }
}

// ---- prep: W1T[j][k] = W1[k][j]  (80 x 256) ----
__global__ __launch_bounds__(256) void k_prep_w1t(const float* __restrict__ W1,
                                                  float* __restrict__ W1T) {
  int j = blockIdx.x, k = threadIdx.x;  // grid 80 x 256
  W1T[j * 256 + k] = W1[k * 80 + j];
}

// ---- core: block = one b, 4 waves. wave wv owns j in [9wv, 9wv+9).
// lane l handles t = l, 64+l, 128+l, 192+l (last valid iff l<8).
// Weights live in VGPRs (lane k holds row k); broadcast via v_readlane.
// PASS 1: per-b stats partials.  PASS 2: dice+w, fused pool/concat/MLP1.
template<int PASS>
__global__ __launch_bounds__(256, 3) void k_core4(
    const int* __restrict__ hist, const int* __restrict__ item,
    const int* __restrict__ user, const int* __restrict__ cate,
    const float* __restrict__ Itab, const float* __restrict__ Utab,
    const float* __restrict__ Ctab, const float* __restrict__ WE,
    const float* __restrict__ WD, const float* __restrict__ TBuf,
    const float* __restrict__ AUST, const float* __restrict__ auA1,
    const float* __restrict__ auW2, const float* __restrict__ auB2,
    const float* __restrict__ W1T, const float* __restrict__ b1,
    float* __restrict__ PART, float* __restrict__ Y1) {
  const int b = blockIdx.x, tid = threadIdx.x;
  const int wv = tid >> 6, l = tid & 63;
  __shared__ float sIe[64];
  __shared__ float sTB[36];
  __shared__ float sWp[(PASS == 2) ? 4 : 1][(PASS == 2) ? 256 : 1];
  __shared__ float sW[(PASS == 2) ? TT : 1];
  __shared__ float sPart[(PASS == 2) ? 256 : 1];
  __shared__ float sX[(PASS == 2) ? 256 : 1];

  const float ie_l = Itab[(size_t)item[b] * 64 + l];
  if (tid < 64) sIe[tid] = ie_l;
  if (tid >= 64 && tid < 100) sTB[tid - 64] = TBuf[b * 36 + (tid - 64)];
  __syncthreads();

  // per-lane weights: row k=l of this wave's 9 columns
  const int jbase = wv * 9;
  float wcol[9];
#pragma unroll
  for (int jj = 0; jj < 9; ++jj) {
    int idx = l * 36 + jbase + jj;
    wcol[jj] = WE[idx] + ie_l * WD[idx];
  }

  // history rows for the 4 t-slots (slot 3 clamped for l>=8)
  const int* hp = hist + b * TT;
  int rows[4];
#pragma unroll
  for (int m = 0; m < 4; ++m) {
    int t = m * 64 + l;
    rows[m] = hp[t < TT ? t : (TT - 1)];
  }

  float acc[4][9];
#pragma unroll
  for (int m = 0; m < 4; ++m)
#pragma unroll
    for (int jj = 0; jj < 9; ++jj) acc[m][jj] = 0.f;

#pragma unroll
  for (int kc = 0; kc < 4; ++kc) {
    float qf[4][16];
#pragma unroll
    for (int m = 0; m < 4; ++m) {
      const float4* rp = (const float4*)(Itab + (size_t)rows[m] * 64) + kc * 4;
      float4 v0 = rp[0], v1 = rp[1], v2 = rp[2], v3 = rp[3];
      qf[m][0] = v0.x; qf[m][1] = v0.y; qf[m][2] = v0.z; qf[m][3] = v0.w;
      qf[m][4] = v1.x; qf[m][5] = v1.y; qf[m][6] = v1.z; qf[m][7] = v1.w;
      qf[m][8] = v2.x; qf[m][9] = v2.y; qf[m][10] = v2.z; qf[m][11] = v2.w;
      qf[m][12] = v3.x; qf[m][13] = v3.y; qf[m][14] = v3.z; qf[m][15] = v3.w;
    }
#pragma unroll
    for (int kk = 0; kk < 16; ++kk) {
      const int k = kc * 16 + kk;
      float sw[9];
#pragma unroll
      for (int jj = 0; jj < 9; ++jj)
        sw[jj] = __int_as_float(
            __builtin_amdgcn_readlane(__float_as_int(wcol[jj]), k));
#pragma unroll
      for (int m = 0; m < 4; ++m) {
        float hk = qf[m][kk];
#pragma unroll
        for (int jj = 0; jj < 9; ++jj)
          acc[m][jj] = fmaf(hk, sw[jj], acc[m][jj]);
      }
    }
  }

  // add tb
  float tb9[9];
#pragma unroll
  for (int jj = 0; jj < 9; ++jj) tb9[jj] = sTB[jbase + jj];
#pragma unroll
  for (int m = 0; m < 4; ++m)
#pragma unroll
    for (int jj = 0; jj < 9; ++jj) acc[m][jj] += tb9[jj];

  if (PASS == 1) {
    float s1[9], s2[9];
#pragma unroll
    for (int jj = 0; jj < 9; ++jj) { s1[jj] = 0.f; s2[jj] = 0.f; }
#pragma unroll
    for (int m = 0; m < 3; ++m)
#pragma unroll
      for (int jj = 0; jj < 9; ++jj) {
        float x = acc[m][jj];
        s1[jj] += x;
        s2[jj] = fmaf(x, x, s2[jj]);
      }
    if (l < 8) {
#pragma unroll
      for (int jj = 0; jj < 9; ++jj) {
        float x = acc[3][jj];
        s1[jj] += x;
        s2[jj] = fmaf(x, x, s2[jj]);
      }
    }
#pragma unroll
    for (int jj = 0; jj < 9; ++jj) {
      float a = s1[jj], q = s2[jj];
      for (int off = 1; off < 64; off <<= 1) {
        a += __shfl_xor(a, off, 64);
        q += __shfl_xor(q, off, 64);
      }
      if (l == 0) {
        PART[b * 72 + jbase + jj] = a;
        PART[b * 72 + 36 + jbase + jj] = q;
      }
    }
  } else {
    // dice + partial attention weight over this wave's 9 channels
    float dmu[9], drs[9], dal[9], dw2[9];
#pragma unroll
    for (int jj = 0; jj < 9; ++jj) {
      dmu[jj] = AUST[jbase + jj];
      drs[jj] = AUST[36 + jbase + jj];
      dal[jj] = auA1[jbase + jj];
      dw2[jj] = auW2[jbase + jj];
    }
#pragma unroll
    for (int m = 0; m < 4; ++m) {
      float pw = 0.f;
#pragma unroll
      for (int jj = 0; jj < 9; ++jj) {
        float x = acc[m][jj];
        float xh = (x - dmu[jj]) * drs[jj];
        float p = 1.0f / (1.0f + __expf(-xh));
        pw = fmaf(x * (dal[jj] + p * (1.0f - dal[jj])), dw2[jj], pw);
      }
      sWp[wv][m * 64 + l] = pw;
    }
    __syncthreads();
    if (tid < TT)
      sW[tid] = auB2[0] + sWp[0][tid] + sWp[1][tid] + sWp[2][tid] + sWp[3][tid];
    __syncthreads();
    // pool: wave wv covers t in [wv*50, wv*50+50); lane l = channel d
    {
      float c = 0.f;
      int t0 = wv * 50;
      for (int u = t0; u < t0 + 50; ++u) {
        int r = hp[u];                                  // wave-uniform
        c = fmaf(sW[u], Itab[(size_t)r * 64 + l], c);   // coalesced 256B
      }
      sPart[tid] = c;
    }
    __syncthreads();
    if (tid < 64) {
      float cur = sPart[tid] + sPart[64 + tid] + sPart[128 + tid] + sPart[192 + tid];
      sX[tid] = Utab[(size_t)user[b] * 64 + tid];
      sX[64 + tid] = sIe[tid];
      sX[128 + tid] = Ctab[(size_t)cate[b] * 64 + tid];
      sX[192 + tid] = cur;
    }
    __syncthreads();
    if (tid < 80) {
      float a = b1[tid];
      const float4* wt = (const float4*)(W1T + tid * 256);
      for (int kq = 0; kq < 64; ++kq) {
        float4 wv4 = wt[kq];
        a = fmaf(sX[kq * 4 + 0], wv4.x, a);
        a = fmaf(sX[kq * 4 + 1], wv4.y, a);
        a = fmaf(sX[kq * 4 + 2], wv4.z, a);
        a = fmaf(sX[kq * 4 + 3], wv4.w, a);
      }
      Y1[b * 80 + tid] = a;
    }
  }
}

// ---- AU stats finalize ----
__global__ __launch_bounds__(256) void k_aust(const float* __restrict__ PART,
                                              float* __restrict__ AUST) {
  int ch = blockIdx.x, tid = threadIdx.x;  // grid 36
  float s1 = 0.f, s2 = 0.f;
  for (int b = tid; b < BB; b += 256) {
    s1 += PART[b * 72 + ch];
    s2 += PART[b * 72 + 36 + ch];
  }
  __shared__ float r1[256], r2[256];
  r1[tid] = s1;
  r2[tid] = s2;
  __syncthreads();
  for (int off = 128; off > 0; off >>= 1) {
    if (tid < off) { r1[tid] += r1[tid + off]; r2[tid] += r2[tid + off]; }
    __syncthreads();
  }
  if (tid == 0) {
    float m = r1[0] / (float)NT;
    float var = r2[0] / (float)NT - m * m;
    AUST[ch] = m;
    AUST[36 + ch] = 1.0f / sqrtf(var + 1e-8f);
  }
}

// ---- per-channel batch stats over [B, nch] ----
__global__ __launch_bounds__(256) void k_colstats(const float* __restrict__ src,
                                                  int nch, float* __restrict__ st) {
  int ch = blockIdx.x, tid = threadIdx.x;
  float s1 = 0.f, s2 = 0.f;
  for (int r = tid; r < BB; r += 256) {
    float v = src[r * nch + ch];
    s1 += v;
    s2 += v * v;
  }
  __shared__ float r1[256], r2[256];
  r1[tid] = s1;
  r2[tid] = s2;
  __syncthreads();
  for (int off = 128; off > 0; off >>= 1) {
    if (tid < off) { r1[tid] += r1[tid + off]; r2[tid] += r2[tid + off]; }
    __syncthreads();
  }
  if (tid == 0) {
    float m = r1[0] / (float)BB;
    float var = r2[0] / (float)BB - m * m;
    st[ch] = m;
    st[nch + ch] = 1.0f / sqrtf(var + 1e-8f);
  }
}

// ---- MLP layer 2 ----
__global__ __launch_bounds__(128) void k_mlp2(const float* __restrict__ Y1,
                                              const float* __restrict__ ST80,
                                              const float* __restrict__ a1,
                                              const float* __restrict__ W2,
                                              const float* __restrict__ b2,
                                              float* __restrict__ Y2) {
  int b = blockIdx.x, tid = threadIdx.x;
  __shared__ float sY[80];
  if (tid < 80) {
    float x = Y1[b * 80 + tid];
    float xh = (x - ST80[tid]) * ST80[80 + tid];
    float p = 1.0f / (1.0f + expf(-xh));
    sY[tid] = p * x + (1.0f - p) * a1[tid] * x;
  }
  __syncthreads();
  if (tid < 40) {
    float a = b2[tid];
    for (int k = 0; k < 80; ++k) a += sY[k] * W2[k * 40 + tid];
    Y2[b * 40 + tid] = a;
  }
}

// ---- MLP layer 3 ----
__global__ __launch_bounds__(64) void k_mlp3(const float* __restrict__ Y2,
                                             const float* __restrict__ ST40,
                                             const float* __restrict__ a2,
                                             const float* __restrict__ W3,
                                             const float* __restrict__ b3,
                                             float* __restrict__ out) {
  int b = blockIdx.x, tid = threadIdx.x;
  __shared__ float sY[40];
  if (tid < 40) {
    float x = Y2[b * 40 + tid];
    float xh = (x - ST40[tid]) * ST40[40 + tid];
    float p = 1.0f / (1.0f + expf(-xh));
    sY[tid] = p * x + (1.0f - p) * a2[tid] * x;
  }
  __syncthreads();
  if (tid < 2) {
    float a = b3[tid];
    for (int k = 0; k < 40; ++k) a += sY[k] * W3[k * 2 + tid];
    out[b * 2 + tid] = a;
  }
}

extern "C" void kernel_launch(void* const* d_in, const int* in_sizes, int n_in,
                              void* d_out, int out_size, void* d_ws, size_t ws_size,
                              hipStream_t stream) {
  const int* user = (const int*)d_in[0];
  const int* hist = (const int*)d_in[1];
  const int* item = (const int*)d_in[2];
  const int* cate = (const int*)d_in[3];
  const float* Utab = (const float*)d_in[4];
  const float* Itab = (const float*)d_in[5];
  const float* Ctab = (const float*)d_in[6];
  const float* auW1 = (const float*)d_in[7];
  const float* auB1 = (const float*)d_in[8];
  const float* auA1 = (const float*)d_in[9];
  const float* auW2 = (const float*)d_in[10];
  const float* auB2 = (const float*)d_in[11];
  const float* W1 = (const float*)d_in[12];
  const float* b1 = (const float*)d_in[13];
  const float* a1 = (const float*)d_in[14];
  const float* W2 = (const float*)d_in[15];
  const float* b2 = (const float*)d_in[16];
  const float* a2 = (const float*)d_in[17];
  const float* W3 = (const float*)d_in[18];
  const float* b3 = (const float*)d_in[19];
  float* out = (float*)d_out;

  float* ws = (float*)d_ws;
  float* WE = ws;                         // 2304
  float* TBuf = WE + 2304;                // BB*36
  float* PART = TBuf + BB * 36;           // BB*72
  float* AUST = PART + BB * 72;           // 72
  float* Y1 = AUST + 72;                  // BB*80
  float* ST80 = Y1 + BB * 80;             // 160
  float* Y2 = ST80 + 160;                 // BB*40
  float* ST40 = Y2 + BB * 40;             // 80
  float* W1T = ST40 + 80;                 // 80*256

  const float* WD = auW1 + 192 * 36;

  k_prep_we<<<9, 256, 0, stream>>>(auW1, WE);
  k_prep_tb<<<BB, 64, 0, stream>>>(item, Itab, auW1, auB1, TBuf);
  k_prep_w1t<<<80, 256, 0, stream>>>(W1, W1T);
  k_core4<1><<<BB, 256, 0, stream>>>(hist, item, user, cate, Itab, Utab, Ctab,
                                     WE, WD, TBuf, nullptr, nullptr, nullptr,
                                     nullptr, nullptr, nullptr, PART, nullptr);
  k_aust<<<36, 256, 0, stream>>>(PART, AUST);
  k_core4<2><<<BB, 256, 0, stream>>>(hist, item, user, cate, Itab, Utab, Ctab,
                                     WE, WD, TBuf, AUST, auA1, auW2, auB2,
                                     W1T, b1, nullptr, Y1);
  k_colstats<<<80, 256, 0, stream>>>(Y1, 80, ST80);
  k_mlp2<<<BB, 128, 0, stream>>>(Y1, ST80, a1, W2, b2, Y2);
  k_colstats<<<40, 256, 0, stream>>>(Y2, 40, ST40);
  k_mlp3<<<BB, 64, 0, stream>>>(Y2, ST40, a2, W3, b3, out);
}

// Round 7
// 230.485 us; speedup vs baseline: 1.7858x; 1.7858x over previous
//
#include <hip/hip_runtime.h>
#include <math.h>

#define BB 4096
#define TT 200
#define NT (BB*TT)

typedef __attribute__((ext_vector_type(8))) __bf16 bf16x8;
typedef __attribute__((ext_vector_type(4))) float f32x4;

static __device__ __forceinline__ unsigned short f2b(float f) {
  __bf16 b = (__bf16)f;
  return __builtin_bit_cast(unsigned short, b);
}
static __device__ __forceinline__ float b2f(unsigned short u) {
  return (float)__builtin_bit_cast(__bf16, u);
}

// ---- prep: WE = Wa + Wc ----
__global__ __launch_bounds__(256) void k_prep_we(const float* __restrict__ auW1,
                                                 float* __restrict__ WE) {
  int i = blockIdx.x * 256 + threadIdx.x;
  if (i < 64 * 36) WE[i] = auW1[i] + auW1[128 * 36 + i];
}

// ---- prep: TBuf[b][36] = ie_b @ (Wb - Wc) + au_b1 ----
__global__ __launch_bounds__(64) void k_prep_tb(const int* __restrict__ item,
                                                const float* __restrict__ Itab,
                                                const float* __restrict__ auW1,
                                                const float* __restrict__ auB1,
                                                float* __restrict__ TBuf) {
  int b = blockIdx.x, tid = threadIdx.x;
  __shared__ float sIe[64];
  sIe[tid] = Itab[(size_t)item[b] * 64 + tid];
  __syncthreads();
  if (tid < 36) {
    float a = auB1[tid];
    for (int k = 0; k < 64; ++k)
      a += sIe[k] * (auW1[(64 + k) * 36 + tid] - auW1[(128 + k) * 36 + tid]);
    TBuf[b * 36 + tid] = a;
  }
}

// ---- prep: W1T[j][k] = W1[k][j]  (80 x 256) ----
__global__ __launch_bounds__(256) void k_prep_w1t(const float* __restrict__ W1,
                                                  float* __restrict__ W1T) {
  int j = blockIdx.x, k = threadIdx.x;
  W1T[j * 256 + k] = W1[k * 80 + j];
}

// ---- core: block = one b. MFMA batched GEMM [200x64]@[64x36].
// he staged bf16 in LDS [208][72]; WBT = (WE + ie(x)WD)^T bf16 [48][72].
// 13 M-tiles x 3 N-tiles of mfma_f32_16x16x32_bf16, K=64 in 2 chunks.
// PASS 1: per-b stats partials.  PASS 2: dice+w, pool from LDS, concat, MLP1.
template<int PASS>
__global__ __launch_bounds__(256, 3) void k_coreM(
    const int* __restrict__ hist, const int* __restrict__ item,
    const int* __restrict__ user, const int* __restrict__ cate,
    const float* __restrict__ Itab, const float* __restrict__ Utab,
    const float* __restrict__ Ctab, const float* __restrict__ WE,
    const float* __restrict__ WD, const float* __restrict__ TBuf,
    const float* __restrict__ AUST, const float* __restrict__ auA1,
    const float* __restrict__ auW2, const float* __restrict__ auB2,
    const float* __restrict__ W1T, const float* __restrict__ b1,
    float* __restrict__ PART, float* __restrict__ Y1) {
  const int b = blockIdx.x, tid = threadIdx.x;
  const int wv = tid >> 6, l = tid & 63;
  const int lr = l & 15, lq = l >> 4;
  __shared__ __align__(16) unsigned short sHe[208 * 72];
  __shared__ __align__(16) unsigned short sWBT[48 * 72];
  __shared__ float sIe[64];
  __shared__ float sR1[(PASS == 1) ? 4 * 48 : 1];
  __shared__ float sR2[(PASS == 1) ? 4 * 48 : 1];
  __shared__ float sW[(PASS == 2) ? 208 : 1];
  __shared__ float sPart[(PASS == 2) ? 256 : 1];
  __shared__ float sX[(PASS == 2) ? 256 : 1];

  if (tid < 64) sIe[tid] = Itab[(size_t)item[b] * 64 + tid];
  // stage he -> bf16 LDS (16 threads per row, float4 segments)
  const int* hp = hist + b * TT;
  for (int i = tid; i < 200 * 16; i += 256) {
    int r = i >> 4, q = i & 15;
    const float4 v = ((const float4*)(Itab + (size_t)hp[r] * 64))[q];
    unsigned short* d = sHe + r * 72 + q * 4;
    d[0] = f2b(v.x); d[1] = f2b(v.y); d[2] = f2b(v.z); d[3] = f2b(v.w);
  }
  for (int i = tid; i < 8 * 72; i += 256) sHe[200 * 72 + i] = 0;
  __syncthreads();
  // build WBT[n][k] = WE[k][n] + ie[k]*WD[k][n] (bf16), zero-padded n>=36
  for (int i = tid; i < 64 * 48; i += 256) {
    int k = i / 48, n = i - (i / 48) * 48;
    float w = 0.f;
    if (n < 36) { int idx = k * 36 + n; w = WE[idx] + sIe[k] * WD[idx]; }
    sWBT[n * 72 + k] = f2b(w);
  }
  __syncthreads();

  // per-lane bias for its 3 columns
  float tb3[3];
#pragma unroll
  for (int nt = 0; nt < 3; ++nt) {
    int j = nt * 16 + lr;
    tb3[nt] = (j < 36) ? TBuf[b * 36 + j] : 0.f;
  }

  // B fragments: lane l holds B[k = kh*32 + lq*8 + i][n = lr]
  bf16x8 bf[3][2];
#pragma unroll
  for (int nt = 0; nt < 3; ++nt)
#pragma unroll
    for (int kh = 0; kh < 2; ++kh)
      bf[nt][kh] = *reinterpret_cast<const bf16x8*>(
          sWBT + (nt * 16 + lr) * 72 + kh * 32 + lq * 8);

  f32x4 acc[4][3];
#pragma unroll
  for (int mi = 0; mi < 4; ++mi)
#pragma unroll
    for (int nt = 0; nt < 3; ++nt) acc[mi][nt] = (f32x4){0.f, 0.f, 0.f, 0.f};

#pragma unroll
  for (int mi = 0; mi < 4; ++mi) {
    const int mt = wv + mi * 4;
    if (mt <= 12) {
      const unsigned short* ap = sHe + (mt * 16 + lr) * 72 + lq * 8;
      bf16x8 a0 = *reinterpret_cast<const bf16x8*>(ap);
      bf16x8 a1 = *reinterpret_cast<const bf16x8*>(ap + 32);
#pragma unroll
      for (int nt = 0; nt < 3; ++nt) {
        acc[mi][nt] = __builtin_amdgcn_mfma_f32_16x16x32_bf16(
            a0, bf[nt][0], acc[mi][nt], 0, 0, 0);
        acc[mi][nt] = __builtin_amdgcn_mfma_f32_16x16x32_bf16(
            a1, bf[nt][1], acc[mi][nt], 0, 0, 0);
      }
    }
  }

  if (PASS == 1) {
    float s1[3] = {0.f, 0.f, 0.f}, s2[3] = {0.f, 0.f, 0.f};
#pragma unroll
    for (int mi = 0; mi < 4; ++mi) {
      const int mt = wv + mi * 4;
      if (mt <= 12) {
#pragma unroll
        for (int q = 0; q < 4; ++q) {
          const int t = mt * 16 + lq * 4 + q;
          if (t < 200) {
#pragma unroll
            for (int nt = 0; nt < 3; ++nt) {
              float x = acc[mi][nt][q] + tb3[nt];
              s1[nt] += x;
              s2[nt] = fmaf(x, x, s2[nt]);
            }
          }
        }
      }
    }
#pragma unroll
    for (int nt = 0; nt < 3; ++nt) {
      float a = s1[nt], c = s2[nt];
      a += __shfl_xor(a, 16, 64); a += __shfl_xor(a, 32, 64);
      c += __shfl_xor(c, 16, 64); c += __shfl_xor(c, 32, 64);
      if (l < 16) {
        sR1[wv * 48 + nt * 16 + l] = a;
        sR2[wv * 48 + nt * 16 + l] = c;
      }
    }
    __syncthreads();
    if (tid < 36) {
      float a = sR1[tid] + sR1[48 + tid] + sR1[96 + tid] + sR1[144 + tid];
      float c = sR2[tid] + sR2[48 + tid] + sR2[96 + tid] + sR2[144 + tid];
      PART[b * 72 + tid] = a;
      PART[b * 72 + 36 + tid] = c;
    }
  } else {
    float dmu[3], drs[3], dal[3], dw2[3];
#pragma unroll
    for (int nt = 0; nt < 3; ++nt) {
      int j = nt * 16 + lr;
      bool v = j < 36;
      dmu[nt] = v ? AUST[j] : 0.f;
      drs[nt] = v ? AUST[36 + j] : 0.f;
      dal[nt] = v ? auA1[j] : 0.f;
      dw2[nt] = v ? auW2[j] : 0.f;
    }
    const float wb2 = auB2[0];
#pragma unroll
    for (int mi = 0; mi < 4; ++mi) {
      const int mt = wv + mi * 4;
      if (mt <= 12) {
        float pw[4];
#pragma unroll
        for (int q = 0; q < 4; ++q) {
          float p_ = 0.f;
#pragma unroll
          for (int nt = 0; nt < 3; ++nt) {
            float x = acc[mi][nt][q] + tb3[nt];
            float xh = (x - dmu[nt]) * drs[nt];
            float p = 1.0f / (1.0f + __expf(-xh));
            p_ = fmaf(x * (dal[nt] + p * (1.0f - dal[nt])), dw2[nt], p_);
          }
          pw[q] = p_;
        }
#pragma unroll
        for (int q = 0; q < 4; ++q) {
          pw[q] += __shfl_xor(pw[q], 1, 64);
          pw[q] += __shfl_xor(pw[q], 2, 64);
          pw[q] += __shfl_xor(pw[q], 4, 64);
          pw[q] += __shfl_xor(pw[q], 8, 64);
        }
        const int tb_ = mt * 16 + lq * 4;
        if (lr == 0 && tb_ + 0 < 200) sW[tb_ + 0] = wb2 + pw[0];
        if (lr == 1 && tb_ + 1 < 200) sW[tb_ + 1] = wb2 + pw[1];
        if (lr == 2 && tb_ + 2 < 200) sW[tb_ + 2] = wb2 + pw[2];
        if (lr == 3 && tb_ + 3 < 200) sW[tb_ + 3] = wb2 + pw[3];
      }
    }
    __syncthreads();
    // pool from LDS bf16 he: wave wv covers 50 rows, lane l = channel d
    {
      float c = 0.f;
      const int t0 = wv * 50;
      for (int u = t0; u < t0 + 50; ++u)
        c = fmaf(sW[u], b2f(sHe[u * 72 + l]), c);
      sPart[tid] = c;
    }
    __syncthreads();
    if (tid < 64) {
      float cur = sPart[tid] + sPart[64 + tid] + sPart[128 + tid] + sPart[192 + tid];
      sX[tid] = Utab[(size_t)user[b] * 64 + tid];
      sX[64 + tid] = sIe[tid];
      sX[128 + tid] = Ctab[(size_t)cate[b] * 64 + tid];
      sX[192 + tid] = cur;
    }
    __syncthreads();
    if (tid < 80) {
      float a = b1[tid];
      const float4* wt = (const float4*)(W1T + tid * 256);
#pragma unroll 8
      for (int kq = 0; kq < 64; ++kq) {
        float4 w4 = wt[kq];
        a = fmaf(sX[kq * 4 + 0], w4.x, a);
        a = fmaf(sX[kq * 4 + 1], w4.y, a);
        a = fmaf(sX[kq * 4 + 2], w4.z, a);
        a = fmaf(sX[kq * 4 + 3], w4.w, a);
      }
      Y1[b * 80 + tid] = a;
    }
  }
}

// ---- AU stats finalize ----
__global__ __launch_bounds__(256) void k_aust(const float* __restrict__ PART,
                                              float* __restrict__ AUST) {
  int ch = blockIdx.x, tid = threadIdx.x;  // grid 36
  float s1 = 0.f, s2 = 0.f;
  for (int b = tid; b < BB; b += 256) {
    s1 += PART[b * 72 + ch];
    s2 += PART[b * 72 + 36 + ch];
  }
  __shared__ float r1[256], r2[256];
  r1[tid] = s1;
  r2[tid] = s2;
  __syncthreads();
  for (int off = 128; off > 0; off >>= 1) {
    if (tid < off) { r1[tid] += r1[tid + off]; r2[tid] += r2[tid + off]; }
    __syncthreads();
  }
  if (tid == 0) {
    float m = r1[0] / (float)NT;
    float var = r2[0] / (float)NT - m * m;
    AUST[ch] = m;
    AUST[36 + ch] = 1.0f / sqrtf(var + 1e-8f);
  }
}

// ---- per-channel batch stats over [B, nch] ----
__global__ __launch_bounds__(256) void k_colstats(const float* __restrict__ src,
                                                  int nch, float* __restrict__ st) {
  int ch = blockIdx.x, tid = threadIdx.x;
  float s1 = 0.f, s2 = 0.f;
  for (int r = tid; r < BB; r += 256) {
    float v = src[r * nch + ch];
    s1 += v;
    s2 += v * v;
  }
  __shared__ float r1[256], r2[256];
  r1[tid] = s1;
  r2[tid] = s2;
  __syncthreads();
  for (int off = 128; off > 0; off >>= 1) {
    if (tid < off) { r1[tid] += r1[tid + off]; r2[tid] += r2[tid + off]; }
    __syncthreads();
  }
  if (tid == 0) {
    float m = r1[0] / (float)BB;
    float var = r2[0] / (float)BB - m * m;
    st[ch] = m;
    st[nch + ch] = 1.0f / sqrtf(var + 1e-8f);
  }
}

// ---- MLP layer 2 ----
__global__ __launch_bounds__(128) void k_mlp2(const float* __restrict__ Y1,
                                              const float* __restrict__ ST80,
                                              const float* __restrict__ a1,
                                              const float* __restrict__ W2,
                                              const float* __restrict__ b2,
                                              float* __restrict__ Y2) {
  int b = blockIdx.x, tid = threadIdx.x;
  __shared__ float sY[80];
  if (tid < 80) {
    float x = Y1[b * 80 + tid];
    float xh = (x - ST80[tid]) * ST80[80 + tid];
    float p = 1.0f / (1.0f + expf(-xh));
    sY[tid] = p * x + (1.0f - p) * a1[tid] * x;
  }
  __syncthreads();
  if (tid < 40) {
    float a = b2[tid];
    for (int k = 0; k < 80; ++k) a += sY[k] * W2[k * 40 + tid];
    Y2[b * 40 + tid] = a;
  }
}

// ---- MLP layer 3 ----
__global__ __launch_bounds__(64) void k_mlp3(const float* __restrict__ Y2,
                                             const float* __restrict__ ST40,
                                             const float* __restrict__ a2,
                                             const float* __restrict__ W3,
                                             const float* __restrict__ b3,
                                             float* __restrict__ out) {
  int b = blockIdx.x, tid = threadIdx.x;
  __shared__ float sY[40];
  if (tid < 40) {
    float x = Y2[b * 40 + tid];
    float xh = (x - ST40[tid]) * ST40[40 + tid];
    float p = 1.0f / (1.0f + expf(-xh));
    sY[tid] = p * x + (1.0f - p) * a2[tid] * x;
  }
  __syncthreads();
  if (tid < 2) {
    float a = b3[tid];
    for (int k = 0; k < 40; ++k) a += sY[k] * W3[k * 2 + tid];
    out[b * 2 + tid] = a;
  }
}

extern "C" void kernel_launch(void* const* d_in, const int* in_sizes, int n_in,
                              void* d_out, int out_size, void* d_ws, size_t ws_size,
                              hipStream_t stream) {
  const int* user = (const int*)d_in[0];
  const int* hist = (const int*)d_in[1];
  const int* item = (const int*)d_in[2];
  const int* cate = (const int*)d_in[3];
  const float* Utab = (const float*)d_in[4];
  const float* Itab = (const float*)d_in[5];
  const float* Ctab = (const float*)d_in[6];
  const float* auW1 = (const float*)d_in[7];
  const float* auB1 = (const float*)d_in[8];
  const float* auA1 = (const float*)d_in[9];
  const float* auW2 = (const float*)d_in[10];
  const float* auB2 = (const float*)d_in[11];
  const float* W1 = (const float*)d_in[12];
  const float* b1 = (const float*)d_in[13];
  const float* a1 = (const float*)d_in[14];
  const float* W2 = (const float*)d_in[15];
  const float* b2 = (const float*)d_in[16];
  const float* a2 = (const float*)d_in[17];
  const float* W3 = (const float*)d_in[18];
  const float* b3 = (const float*)d_in[19];
  float* out = (float*)d_out;

  float* ws = (float*)d_ws;
  float* WE = ws;                         // 2304
  float* TBuf = WE + 2304;                // BB*36
  float* PART = TBuf + BB * 36;           // BB*72
  float* AUST = PART + BB * 72;           // 72
  float* Y1 = AUST + 72;                  // BB*80
  float* ST80 = Y1 + BB * 80;             // 160
  float* Y2 = ST80 + 160;                 // BB*40
  float* ST40 = Y2 + BB * 40;             // 80
  float* W1T = ST40 + 80;                 // 80*256

  const float* WD = auW1 + 192 * 36;

  k_prep_we<<<9, 256, 0, stream>>>(auW1, WE);
  k_prep_tb<<<BB, 64, 0, stream>>>(item, Itab, auW1, auB1, TBuf);
  k_prep_w1t<<<80, 256, 0, stream>>>(W1, W1T);
  k_coreM<1><<<BB, 256, 0, stream>>>(hist, item, user, cate, Itab, Utab, Ctab,
                                     WE, WD, TBuf, nullptr, nullptr, nullptr,
                                     nullptr, nullptr, nullptr, PART, nullptr);
  k_aust<<<36, 256, 0, stream>>>(PART, AUST);
  k_coreM<2><<<BB, 256, 0, stream>>>(hist, item, user, cate, Itab, Utab, Ctab,
                                     WE, WD, TBuf, AUST, auA1, auW2, auB2,
                                     W1T, b1, nullptr, Y1);
  k_colstats<<<80, 256, 0, stream>>>(Y1, 80, ST80);
  k_mlp2<<<BB, 128, 0, stream>>>(Y1, ST80, a1, W2, b2, Y2);
  k_colstats<<<40, 256, 0, stream>>>(Y2, 40, ST40);
  k_mlp3<<<BB, 64, 0, stream>>>(Y2, ST40, a2, W3, b3, out);
}

// Round 8
// 201.105 us; speedup vs baseline: 2.0467x; 1.1461x over previous
//
#include <hip/hip_runtime.h>
#include <math.h>

#define BB 4096
#define TT 200
#define NT (BB*TT)

typedef __attribute__((ext_vector_type(8))) __bf16 bf16x8;
typedef __attribute__((ext_vector_type(4))) float f32x4;
typedef __attribute__((ext_vector_type(2))) _Float16 f16x2;

static __device__ __forceinline__ unsigned short f2b(float f) {
  __bf16 b = (__bf16)f;
  return __builtin_bit_cast(unsigned short, b);
}

// ---- prep: WE = Wa + Wc ----
__global__ __launch_bounds__(256) void k_prep_we(const float* __restrict__ auW1,
                                                 float* __restrict__ WE) {
  int i = blockIdx.x * 256 + threadIdx.x;
  if (i < 64 * 36) WE[i] = auW1[i] + auW1[128 * 36 + i];
}

// ---- prep: TBuf[b][36] = ie_b @ (Wb - Wc) + au_b1 ----
__global__ __launch_bounds__(64) void k_prep_tb(const int* __restrict__ item,
                                                const float* __restrict__ Itab,
                                                const float* __restrict__ auW1,
                                                const float* __restrict__ auB1,
                                                float* __restrict__ TBuf) {
  int b = blockIdx.x, tid = threadIdx.x;
  __shared__ float sIe[64];
  sIe[tid] = Itab[(size_t)item[b] * 64 + tid];
  __syncthreads();
  if (tid < 36) {
    float a = auB1[tid];
    for (int k = 0; k < 64; ++k)
      a += sIe[k] * (auW1[(64 + k) * 36 + tid] - auW1[(128 + k) * 36 + tid]);
    TBuf[b * 36 + tid] = a;
  }
}

// ---- prep: W1T[j][k] = W1[k][j]  (80 x 256) ----
__global__ __launch_bounds__(256) void k_prep_w1t(const float* __restrict__ W1,
                                                  float* __restrict__ W1T) {
  int j = blockIdx.x, k = threadIdx.x;
  W1T[j * 256 + k] = W1[k * 80 + j];
}

// ---- K1: per-b GEMM [200x64]@[64x36] with A direct global->reg.
// Emits stats partials + X (f16 preactivations incl. bias).
__global__ __launch_bounds__(256, 4) void k_gemm1(
    const int* __restrict__ hist, const int* __restrict__ item,
    const float* __restrict__ Itab, const float* __restrict__ WE,
    const float* __restrict__ WD, const float* __restrict__ TBuf,
    float* __restrict__ PART, _Float16* __restrict__ Xb) {
  const int b = blockIdx.x, tid = threadIdx.x;
  const int wv = tid >> 6, l = tid & 63;
  const int lr = l & 15, lq = l >> 4;
  __shared__ __align__(16) unsigned short sWBT[48 * 72];
  __shared__ float sIe[64];
  __shared__ float sR1[192], sR2[192];

  if (tid < 64) sIe[tid] = Itab[(size_t)item[b] * 64 + tid];
  __syncthreads();
  for (int i = tid; i < 64 * 48; i += 256) {
    int k = i / 48, n = i - (i / 48) * 48;
    float w = 0.f;
    if (n < 36) { int idx = k * 36 + n; w = WE[idx] + sIe[k] * WD[idx]; }
    sWBT[n * 72 + k] = f2b(w);
  }
  __syncthreads();

  // B fragments: lane holds B[k = kh*32 + lq*8 + i][n = lr] for 3 n-tiles
  bf16x8 bfr[3][2];
#pragma unroll
  for (int nt = 0; nt < 3; ++nt)
#pragma unroll
    for (int kh = 0; kh < 2; ++kh)
      bfr[nt][kh] = *reinterpret_cast<const bf16x8*>(
          sWBT + (nt * 16 + lr) * 72 + kh * 32 + lq * 8);

  float tb3[3];
#pragma unroll
  for (int nt = 0; nt < 3; ++nt) {
    int j = nt * 16 + lr;
    tb3[nt] = (j < 36) ? TBuf[b * 36 + j] : 0.f;
  }

  const int* hp = hist + b * TT;
  f32x4 acc[4][3];
#pragma unroll
  for (int mi = 0; mi < 4; ++mi)
#pragma unroll
    for (int nt = 0; nt < 3; ++nt) acc[mi][nt] = (f32x4){0.f, 0.f, 0.f, 0.f};

#pragma unroll
  for (int mi = 0; mi < 4; ++mi) {
    const int mt = wv + mi * 4;
    if (mt <= 12) {
      int trow = mt * 16 + lr;
      int row = hp[trow < TT ? trow : (TT - 1)];
      const float* rp = Itab + (size_t)row * 64;
      const float4* rp4 = (const float4*)(rp + lq * 8);
      float4 v0 = rp4[0];
      float4 v1 = rp4[1];
      const float4* rp4b = (const float4*)(rp + 32 + lq * 8);
      float4 v2 = rp4b[0];
      float4 v3 = rp4b[1];
      bf16x8 a0, a1;
      a0[0] = (__bf16)v0.x; a0[1] = (__bf16)v0.y; a0[2] = (__bf16)v0.z; a0[3] = (__bf16)v0.w;
      a0[4] = (__bf16)v1.x; a0[5] = (__bf16)v1.y; a0[6] = (__bf16)v1.z; a0[7] = (__bf16)v1.w;
      a1[0] = (__bf16)v2.x; a1[1] = (__bf16)v2.y; a1[2] = (__bf16)v2.z; a1[3] = (__bf16)v2.w;
      a1[4] = (__bf16)v3.x; a1[5] = (__bf16)v3.y; a1[6] = (__bf16)v3.z; a1[7] = (__bf16)v3.w;
#pragma unroll
      for (int nt = 0; nt < 3; ++nt) {
        acc[mi][nt] = __builtin_amdgcn_mfma_f32_16x16x32_bf16(
            a0, bfr[nt][0], acc[mi][nt], 0, 0, 0);
        acc[mi][nt] = __builtin_amdgcn_mfma_f32_16x16x32_bf16(
            a1, bfr[nt][1], acc[mi][nt], 0, 0, 0);
      }
    }
  }

  // stats + X store.  C mapping: t = mt*16 + lq*4 + q, j = nt*16 + lr.
  float s1[3] = {0.f, 0.f, 0.f}, s2[3] = {0.f, 0.f, 0.f};
  _Float16* xrow = Xb + (size_t)b * 7200;
#pragma unroll
  for (int mi = 0; mi < 4; ++mi) {
    const int mt = wv + mi * 4;
    if (mt <= 12) {
#pragma unroll
      for (int q = 0; q < 4; ++q) {
        const int t = mt * 16 + lq * 4 + q;
        if (t < TT) {
#pragma unroll
          for (int nt = 0; nt < 3; ++nt) {
            const int j = nt * 16 + lr;
            float x = acc[mi][nt][q] + tb3[nt];
            if (j < 36) {
              s1[nt] += x;
              s2[nt] = fmaf(x, x, s2[nt]);
              xrow[t * 36 + j] = (_Float16)x;
            }
          }
        }
      }
    }
  }
#pragma unroll
  for (int nt = 0; nt < 3; ++nt) {
    float a = s1[nt], c = s2[nt];
    a += __shfl_xor(a, 16, 64); a += __shfl_xor(a, 32, 64);
    c += __shfl_xor(c, 16, 64); c += __shfl_xor(c, 32, 64);
    if (l < 16) {
      sR1[wv * 48 + nt * 16 + l] = a;
      sR2[wv * 48 + nt * 16 + l] = c;
    }
  }
  __syncthreads();
  if (tid < 36) {
    float a = sR1[tid] + sR1[48 + tid] + sR1[96 + tid] + sR1[144 + tid];
    float c = sR2[tid] + sR2[48 + tid] + sR2[96 + tid] + sR2[144 + tid];
    PART[b * 72 + tid] = a;
    PART[b * 72 + 36 + tid] = c;
  }
}

// ---- AU stats finalize ----
__global__ __launch_bounds__(256) void k_aust(const float* __restrict__ PART,
                                              float* __restrict__ AUST) {
  int ch = blockIdx.x, tid = threadIdx.x;  // grid 36
  float s1 = 0.f, s2 = 0.f;
  for (int b = tid; b < BB; b += 256) {
    s1 += PART[b * 72 + ch];
    s2 += PART[b * 72 + 36 + ch];
  }
  __shared__ float r1[256], r2[256];
  r1[tid] = s1;
  r2[tid] = s2;
  __syncthreads();
  for (int off = 128; off > 0; off >>= 1) {
    if (tid < off) { r1[tid] += r1[tid + off]; r2[tid] += r2[tid + off]; }
    __syncthreads();
  }
  if (tid == 0) {
    float m = r1[0] / (float)NT;
    float var = r2[0] / (float)NT - m * m;
    AUST[ch] = m;
    AUST[36 + ch] = 1.0f / sqrtf(var + 1e-8f);
  }
}

// ---- K2: read X, dice+w, pool (L3-hot gather), concat, MLP1 ----
__global__ __launch_bounds__(256) void k_att(
    const int* __restrict__ hist, const int* __restrict__ user,
    const int* __restrict__ item, const int* __restrict__ cate,
    const float* __restrict__ Itab, const float* __restrict__ Utab,
    const float* __restrict__ Ctab, const _Float16* __restrict__ Xb,
    const float* __restrict__ AUST, const float* __restrict__ auA1,
    const float* __restrict__ auW2, const float* __restrict__ auB2,
    const float* __restrict__ W1T, const float* __restrict__ b1,
    float* __restrict__ Y1) {
  const int b = blockIdx.x, tid = threadIdx.x;
  __shared__ float sW[TT];
  __shared__ int sRows[TT];
  __shared__ float sD[144];
  __shared__ float sPart[256];
  __shared__ float sX[256];
  if (tid < TT) sRows[tid] = hist[b * TT + tid];
  if (tid >= 208 && tid < 208 + 36) sD[tid - 208] = AUST[tid - 208];
  else if (tid < 36) sD[36 + tid] = AUST[36 + tid];
  else if (tid >= 64 && tid < 100) sD[72 + (tid - 64)] = auA1[tid - 64];
  else if (tid >= 128 && tid < 164) sD[108 + (tid - 128)] = auW2[tid - 128];
  __syncthreads();
  if (tid < TT) {
    const f16x2* xr = (const f16x2*)(Xb + (size_t)b * 7200 + tid * 36);
    float w = auB2[0];
#pragma unroll
    for (int p = 0; p < 18; ++p) {
      f16x2 pr = xr[p];
#pragma unroll
      for (int h = 0; h < 2; ++h) {
        int j = 2 * p + h;
        float x = (float)pr[h];
        float xh = (x - sD[j]) * sD[36 + j];
        float pp = 1.0f / (1.0f + __expf(-xh));
        float al = sD[72 + j];
        w = fmaf(x * (al + pp * (1.0f - al)), sD[108 + j], w);
      }
    }
    sW[tid] = w;
  }
  __syncthreads();
  {
    const int l = tid & 63, wv = tid >> 6;
    float c = 0.f;
    const int t0 = wv * 50;
#pragma unroll 5
    for (int u = t0; u < t0 + 50; ++u) {
      int r = sRows[u];
      c = fmaf(sW[u], Itab[(size_t)r * 64 + l], c);
    }
    sPart[tid] = c;
  }
  __syncthreads();
  if (tid < 64) {
    float cur = sPart[tid] + sPart[64 + tid] + sPart[128 + tid] + sPart[192 + tid];
    sX[tid] = Utab[(size_t)user[b] * 64 + tid];
    sX[64 + tid] = Itab[(size_t)item[b] * 64 + tid];
    sX[128 + tid] = Ctab[(size_t)cate[b] * 64 + tid];
    sX[192 + tid] = cur;
  }
  __syncthreads();
  if (tid < 80) {
    float a = b1[tid];
    const float4* wt = (const float4*)(W1T + tid * 256);
#pragma unroll 8
    for (int kq = 0; kq < 64; ++kq) {
      float4 w4 = wt[kq];
      a = fmaf(sX[kq * 4 + 0], w4.x, a);
      a = fmaf(sX[kq * 4 + 1], w4.y, a);
      a = fmaf(sX[kq * 4 + 2], w4.z, a);
      a = fmaf(sX[kq * 4 + 3], w4.w, a);
    }
    Y1[b * 80 + tid] = a;
  }
}

// ---- per-channel batch stats over [B, nch] ----
__global__ __launch_bounds__(256) void k_colstats(const float* __restrict__ src,
                                                  int nch, float* __restrict__ st) {
  int ch = blockIdx.x, tid = threadIdx.x;
  float s1 = 0.f, s2 = 0.f;
  for (int r = tid; r < BB; r += 256) {
    float v = src[r * nch + ch];
    s1 += v;
    s2 += v * v;
  }
  __shared__ float r1[256], r2[256];
  r1[tid] = s1;
  r2[tid] = s2;
  __syncthreads();
  for (int off = 128; off > 0; off >>= 1) {
    if (tid < off) { r1[tid] += r1[tid + off]; r2[tid] += r2[tid + off]; }
    __syncthreads();
  }
  if (tid == 0) {
    float m = r1[0] / (float)BB;
    float var = r2[0] / (float)BB - m * m;
    st[ch] = m;
    st[nch + ch] = 1.0f / sqrtf(var + 1e-8f);
  }
}

// ---- MLP layer 2 ----
__global__ __launch_bounds__(128) void k_mlp2(const float* __restrict__ Y1,
                                              const float* __restrict__ ST80,
                                              const float* __restrict__ a1,
                                              const float* __restrict__ W2,
                                              const float* __restrict__ b2,
                                              float* __restrict__ Y2) {
  int b = blockIdx.x, tid = threadIdx.x;
  __shared__ float sY[80];
  if (tid < 80) {
    float x = Y1[b * 80 + tid];
    float xh = (x - ST80[tid]) * ST80[80 + tid];
    float p = 1.0f / (1.0f + expf(-xh));
    sY[tid] = p * x + (1.0f - p) * a1[tid] * x;
  }
  __syncthreads();
  if (tid < 40) {
    float a = b2[tid];
    for (int k = 0; k < 80; ++k) a += sY[k] * W2[k * 40 + tid];
    Y2[b * 40 + tid] = a;
  }
}

// ---- MLP layer 3 ----
__global__ __launch_bounds__(64) void k_mlp3(const float* __restrict__ Y2,
                                             const float* __restrict__ ST40,
                                             const float* __restrict__ a2,
                                             const float* __restrict__ W3,
                                             const float* __restrict__ b3,
                                             float* __restrict__ out) {
  int b = blockIdx.x, tid = threadIdx.x;
  __shared__ float sY[40];
  if (tid < 40) {
    float x = Y2[b * 40 + tid];
    float xh = (x - ST40[tid]) * ST40[40 + tid];
    float p = 1.0f / (1.0f + expf(-xh));
    sY[tid] = p * x + (1.0f - p) * a2[tid] * x;
  }
  __syncthreads();
  if (tid < 2) {
    float a = b3[tid];
    for (int k = 0; k < 40; ++k) a += sY[k] * W3[k * 2 + tid];
    out[b * 2 + tid] = a;
  }
}

extern "C" void kernel_launch(void* const* d_in, const int* in_sizes, int n_in,
                              void* d_out, int out_size, void* d_ws, size_t ws_size,
                              hipStream_t stream) {
  const int* user = (const int*)d_in[0];
  const int* hist = (const int*)d_in[1];
  const int* item = (const int*)d_in[2];
  const int* cate = (const int*)d_in[3];
  const float* Utab = (const float*)d_in[4];
  const float* Itab = (const float*)d_in[5];
  const float* Ctab = (const float*)d_in[6];
  const float* auW1 = (const float*)d_in[7];
  const float* auB1 = (const float*)d_in[8];
  const float* auA1 = (const float*)d_in[9];
  const float* auW2 = (const float*)d_in[10];
  const float* auB2 = (const float*)d_in[11];
  const float* W1 = (const float*)d_in[12];
  const float* b1 = (const float*)d_in[13];
  const float* a1 = (const float*)d_in[14];
  const float* W2 = (const float*)d_in[15];
  const float* b2 = (const float*)d_in[16];
  const float* a2 = (const float*)d_in[17];
  const float* W3 = (const float*)d_in[18];
  const float* b3 = (const float*)d_in[19];
  float* out = (float*)d_out;

  float* ws = (float*)d_ws;
  float* WE = ws;                         // 2304
  float* TBuf = WE + 2304;                // BB*36
  float* PART = TBuf + BB * 36;           // BB*72
  float* AUST = PART + BB * 72;           // 72
  float* Y1 = AUST + 72;                  // BB*80
  float* ST80 = Y1 + BB * 80;             // 160
  float* Y2 = ST80 + 160;                 // BB*40
  float* ST40 = Y2 + BB * 40;             // 80
  float* W1T = ST40 + 80;                 // 80*256
  _Float16* Xb = (_Float16*)(W1T + 80 * 256);  // BB*7200 f16 (59 MB)

  const float* WD = auW1 + 192 * 36;

  k_prep_we<<<9, 256, 0, stream>>>(auW1, WE);
  k_prep_tb<<<BB, 64, 0, stream>>>(item, Itab, auW1, auB1, TBuf);
  k_prep_w1t<<<80, 256, 0, stream>>>(W1, W1T);
  k_gemm1<<<BB, 256, 0, stream>>>(hist, item, Itab, WE, WD, TBuf, PART, Xb);
  k_aust<<<36, 256, 0, stream>>>(PART, AUST);
  k_att<<<BB, 256, 0, stream>>>(hist, user, item, cate, Itab, Utab, Ctab, Xb,
                                AUST, auA1, auW2, auB2, W1T, b1, Y1);
  k_colstats<<<80, 256, 0, stream>>>(Y1, 80, ST80);
  k_mlp2<<<BB, 128, 0, stream>>>(Y1, ST80, a1, W2, b2, Y2);
  k_colstats<<<40, 256, 0, stream>>>(Y2, 40, ST40);
  k_mlp3<<<BB, 64, 0, stream>>>(Y2, ST40, a2, W3, b3, out);
}